// Round 13
// baseline (280.261 us; speedup 1.0000x reference)
//
#include <hip/hip_runtime.h>
#include <math.h>

#define HW 784
#define Cc 192
#define Bb 16
#define CO 384
#define KK 9
#define OG 8

typedef __attribute__((ext_vector_type(8))) short bf16x8;
typedef __attribute__((ext_vector_type(4))) float f32x4;

__device__ __forceinline__ unsigned f2ord(float f){
  unsigned u = __float_as_uint(f);
  return (u & 0x80000000u) ? ~u : (u | 0x80000000u);
}

__device__ __forceinline__ unsigned short b16rne(float v){
  unsigned u = __float_as_uint(v);
  unsigned r = u + 0x7FFFu + ((u >> 16) & 1u);
  return (unsigned short)(r >> 16);
}

// ---- 1. per-(b,c) mean & max over HW (float4 rows) ----
__global__ void k_chstats(const float* __restrict__ x, float* __restrict__ chm, float* __restrict__ chx){
  int wid = threadIdx.x >> 6, lane = threadIdx.x & 63;
  int r = blockIdx.x * 4 + wid;               // r in [0, B*C)
  const float4* row = (const float4*)(x + (size_t)r * HW);   // 196 float4s
  float s = 0.f, m = -3.4e38f;
  #pragma unroll
  for (int i = 0; i < 4; ++i){
    int f4 = lane + 64*i;
    if (f4 < 196){
      float4 v = row[f4];
      s += v.x + v.y + v.z + v.w;
      m = fmaxf(m, fmaxf(fmaxf(v.x, v.y), fmaxf(v.z, v.w)));
    }
  }
  for (int off = 32; off; off >>= 1){ s += __shfl_xor(s, off); m = fmaxf(m, __shfl_xor(m, off)); }
  if (lane == 0){ chm[r] = s / (float)HW; chx[r] = m; }
}

// ---- 2. channel-attention MLP: ch = sigmoid(mlp(mean)+mlp(max)) ----
__global__ void k_mlp(const float* __restrict__ chm, const float* __restrict__ chx,
                      const float* __restrict__ w1, const float* __restrict__ b1,
                      const float* __restrict__ w2, const float* __restrict__ b2,
                      float* __restrict__ chv){
  int b = blockIdx.x, t = threadIdx.x;
  __shared__ float vm[Cc], vx[Cc], hp[2][12];
  if (t < Cc){ vm[t] = chm[b*Cc + t]; vx[t] = chx[b*Cc + t]; }
  __syncthreads();
  if (t < 24){
    int h = t % 12;
    const float* src = (t < 12) ? vm : vx;
    float a = b1[h];
    for (int c = 0; c < Cc; ++c) a += src[c] * w1[h*Cc + c];
    hp[t/12][h] = fmaxf(a, 0.f);
  }
  __syncthreads();
  if (t < Cc){
    float a = 2.f * b2[t];
    for (int h = 0; h < 12; ++h) a += (hp[0][h] + hp[1][h]) * w2[t*12 + h];
    chv[b*Cc + t] = 1.f / (1.f + expf(-a));
  }
}

// ---- 3. spatial mean/max over C of x*ch  +  column norms of x (fused) ----
__global__ void k_spin(const float* __restrict__ x, const float* __restrict__ chv,
                       float* __restrict__ amean, float* __restrict__ amax,
                       float* __restrict__ nrm){
  int b = blockIdx.x >> 2;
  int n = ((blockIdx.x & 3) << 8) + threadIdx.x;
  if (n >= HW) return;
  const float* xb = x + (size_t)b*Cc*HW + n;
  const float* cb = chv + b*Cc;
  float s = 0.f, m = -3.4e38f, sq = 0.f;
  for (int c = 0; c < Cc; ++c){
    float xv = xb[(size_t)c*HW];
    float v = xv * cb[c];
    s += v; m = fmaxf(m, v); sq += xv*xv;
  }
  amean[b*HW + n] = s / (float)Cc;
  amax[b*HW + n]  = m;
  nrm[b*HW + n]   = fmaxf(sqrtf(sq), 1e-12f);
}

// ---- 4. 7x7 conv (2 in-ch) + sigmoid ----
__global__ void k_conv(const float* __restrict__ amean, const float* __restrict__ amax,
                       const float* __restrict__ wsp, const float* __restrict__ bsp,
                       float* __restrict__ satt){
  int b = blockIdx.x >> 2;
  int n = ((blockIdx.x & 3) << 8) + threadIdx.x;
  if (n >= HW) return;
  int yy = n / 28, xx = n % 28;
  float a = 0.f;
  for (int ky = 0; ky < 7; ++ky){
    int iy = yy + ky - 3; if (iy < 0 || iy >= 28) continue;
    for (int kx = 0; kx < 7; ++kx){
      int ix = xx + kx - 3; if (ix < 0 || ix >= 28) continue;
      int ii = b*HW + iy*28 + ix;
      a += amean[ii]*wsp[ky*7 + kx] + amax[ii]*wsp[49 + ky*7 + kx];
    }
  }
  satt[b*HW + n] = 1.f / (1.f + expf(-(a + bsp[0])));
}

// ---- 5. attention softmax stats per (b,c): vmax and inv = 1/(1+EPS*S)  (float4 rows) ----
__global__ void k_attstats(const float* __restrict__ x, const float* __restrict__ chv,
                           const float* __restrict__ satt,
                           float* __restrict__ vmaxA, float* __restrict__ invA){
  int wid = threadIdx.x >> 6, lane = threadIdx.x & 63;
  int r = blockIdx.x * 4 + wid;               // b*Cc + c
  int b = r / Cc;
  const float4* row = (const float4*)(x + (size_t)r * HW);
  const float4* sr  = (const float4*)(satt + b * HW);
  float ch = chv[r];
  float4 vv[4];
  float m = -3.4e38f;
  #pragma unroll
  for (int i = 0; i < 4; ++i){
    int f4 = lane + 64*i;
    if (f4 < 196){
      float4 xv = row[f4], sv = sr[f4];
      vv[i].x = (xv.x * ch) * sv.x; vv[i].y = (xv.y * ch) * sv.y;
      vv[i].z = (xv.z * ch) * sv.z; vv[i].w = (xv.w * ch) * sv.w;
      m = fmaxf(m, fmaxf(fmaxf(vv[i].x, vv[i].y), fmaxf(vv[i].z, vv[i].w)));
    }
  }
  for (int off = 32; off; off >>= 1) m = fmaxf(m, __shfl_xor(m, off));
  float s = 0.f;
  #pragma unroll
  for (int i = 0; i < 4; ++i){
    int f4 = lane + 64*i;
    if (f4 < 196){
      s += expf(vv[i].x - m) + expf(vv[i].y - m) + expf(vv[i].z - m) + expf(vv[i].w - m);
    }
  }
  for (int off = 32; off; off >>= 1) s += __shfl_xor(s, off);
  if (lane == 0){ vmaxA[r] = m; invA[r] = 1.f / (1.f + 1e-10f * s); }
}

// ---- 6. merged: transpose+split pass (blocks 0..623)  |  weight prep (blocks 624..1199) ----
__global__ __launch_bounds__(256) void k_cvt2wp(const float* __restrict__ x, const float* __restrict__ nrm,
                                                const float* __restrict__ chv, const float* __restrict__ satt,
                                                const float* __restrict__ vmaxA, const float* __restrict__ invA,
                                                const float* __restrict__ we,
                                                unsigned short* __restrict__ Xnh, unsigned short* __restrict__ Xnl,
                                                unsigned short* __restrict__ XAh, unsigned short* __restrict__ XAl,
                                                unsigned short* __restrict__ Wph, unsigned short* __restrict__ Wpl){
  int bid = blockIdx.x, t = threadIdx.x;
  if (bid >= 624){                         // ---- weight prep path ----
    int i = (bid - 624)*256 + t;           // < 147456 exactly
    int o = i / Cc, c = i % Cc;
    float v = (o < CO) ? (we[(size_t)o*384 + c] - we[(size_t)o*384 + Cc + c])
                       : we[(size_t)(o - CO)*384 + Cc + c];
    unsigned short h = b16rne(v);
    float lo = v - __uint_as_float((unsigned)h << 16);
    Wph[i] = h;
    Wpl[i] = b16rne(lo);
    return;
  }
  // ---- transpose + split path ----
  int xx = bid % 13, yy = (bid / 13) % 3, b = bid / 39;
  int c0 = yy*64, n0 = xx*64;
  __shared__ float T[64][65];
  __shared__ float chs[64], vms[64], ivs[64];
  int nl = (t & 15) * 4, cl = t >> 4;
  const float* xb = x + (size_t)b*Cc*HW;
  #pragma unroll
  for (int r = 0; r < 4; ++r){
    int c_loc = cl + r*16;
    int n = n0 + nl;
    float4 v = (n < HW) ? *(const float4*)(xb + (size_t)(c0 + c_loc)*HW + n) : make_float4(0,0,0,0);
    *(float4*)&T[c_loc][nl] = v;
  }
  if (t < 64){
    chs[t] = chv[b*Cc + c0 + t];
    vms[t] = vmaxA[b*Cc + c0 + t];
    ivs[t] = invA[b*Cc + c0 + t];
  }
  __syncthreads();
  int nr = t >> 2, q = t & 3;
  int n_g = n0 + nr;
  if (n_g >= HW) return;
  float nv = nrm[b*HW + n_g];
  float sr = satt[b*HW + n_g];
  unsigned int nh[8], nlw[8], ah[8], al[8];
  #pragma unroll
  for (int j = 0; j < 8; ++j){
    unsigned int parts[2][2];
    #pragma unroll
    for (int e = 0; e < 2; ++e){
      int cc_ = q*16 + 2*j + e;
      float v = T[cc_][nr];
      float xnv = v / nv;
      unsigned short h0 = b16rne(xnv);
      float l0 = xnv - __uint_as_float((unsigned)h0 << 16);
      parts[0][e] = (unsigned)h0 | ((unsigned)b16rne(l0) << 16);
      float vvv = (v * chs[cc_]) * sr;
      float ex = expf(vvv - vms[cc_]);
      float a = ex * ivs[cc_];
      float xav = v * ((2.f*a - 1.f)*0.025f + 1.f);
      unsigned short h1 = b16rne(xav);
      float l1 = xav - __uint_as_float((unsigned)h1 << 16);
      parts[1][e] = (unsigned)h1 | ((unsigned)b16rne(l1) << 16);
    }
    nh[j]  = (parts[0][0] & 0xFFFFu) | (parts[0][1] << 16);
    nlw[j] = (parts[0][0] >> 16)     | (parts[0][1] & 0xFFFF0000u);
    ah[j]  = (parts[1][0] & 0xFFFFu) | (parts[1][1] << 16);
    al[j]  = (parts[1][0] >> 16)     | (parts[1][1] & 0xFFFF0000u);
  }
  size_t base = ((size_t)b*HW + n_g)*Cc + c0 + q*16;
  *(uint4*)(Xnh + base)     = make_uint4(nh[0], nh[1], nh[2], nh[3]);
  *(uint4*)(Xnh + base + 8) = make_uint4(nh[4], nh[5], nh[6], nh[7]);
  *(uint4*)(Xnl + base)     = make_uint4(nlw[0], nlw[1], nlw[2], nlw[3]);
  *(uint4*)(Xnl + base + 8) = make_uint4(nlw[4], nlw[5], nlw[6], nlw[7]);
  *(uint4*)(XAh + base)     = make_uint4(ah[0], ah[1], ah[2], ah[3]);
  *(uint4*)(XAh + base + 8) = make_uint4(ah[4], ah[5], ah[6], ah[7]);
  *(uint4*)(XAl + base)     = make_uint4(al[0], al[1], al[2], al[3]);
  *(uint4*)(XAl + base + 8) = make_uint4(al[4], al[5], al[6], al[7]);
}

// ---- 7. merged MFMA launch, XCD-swizzled, symmetric gram, prefetch via FULL UNROLL
//      (rule #20: constant indices after unroll -> registers, no scratch).
//      logical blocks: 0..447 = gram upper-tri tiles (mirror-write D^T),
//                      448..1119 = GEMM (PQ). 1120 = 8*140 exactly. ----
__global__ __launch_bounds__(256) void k_gramgemm(const unsigned short* __restrict__ Xnh,
                                                  const unsigned short* __restrict__ Xnl,
                                                  const unsigned short* __restrict__ Wph,
                                                  const unsigned short* __restrict__ Wpl,
                                                  const unsigned short* __restrict__ XAh,
                                                  const unsigned short* __restrict__ XAl,
                                                  float* __restrict__ D, float* __restrict__ PQ){
  __shared__ __align__(16) char smem[32768];
  unsigned short* Als = (unsigned short*)smem;          // 8192 ushorts
  unsigned short* Bls = Als + 8192;                     // 8192 ushorts
  float* Tt = (float*)smem;                             // mirror-transpose staging (16.5KB)

  int hwbid = blockIdx.x;
  int bid = (hwbid & 7) * 140 + (hwbid >> 3);           // XCD-chunk swizzle (bijective, 1120=8*140)
  int t = threadIdx.x, w = t >> 6, l = t & 63;
  int wr = w >> 1, wc = w & 1;
  f32x4 acc[4][4] = {};
  int nn = t >> 1, half = t & 1;

  bool isGram = bid < 448;
  int b, r0, c0, ty = 0, tx = 0;
  const unsigned short *A_h, *A_l, *B_h, *B_l;
  if (isGram){
    b = bid / 28; int rm = bid % 28;
    if      (rm <  7){ ty=0; tx=rm; }
    else if (rm < 13){ ty=1; tx=1+rm-7; }
    else if (rm < 18){ ty=2; tx=2+rm-13; }
    else if (rm < 22){ ty=3; tx=3+rm-18; }
    else if (rm < 25){ ty=4; tx=4+rm-22; }
    else if (rm < 27){ ty=5; tx=5+rm-25; }
    else             { ty=6; tx=6; }
    r0 = ty*128; c0 = tx*128;
    size_t bb = (size_t)b*HW*Cc;
    A_h = Xnh + bb; A_l = Xnl + bb; B_h = Xnh + bb; B_l = Xnl + bb;
  } else {
    int id = bid - 448;
    b = id / 42; int rem = id % 42;
    c0 = (rem % 7) * 128; r0 = (rem / 7) * 128;
    size_t bb = (size_t)b*HW*Cc;
    A_h = Wph; A_l = Wpl; B_h = XAh + bb; B_l = XAl + bb;
  }
  int ra = r0 + nn; if (isGram && ra > HW-1) ra = HW-1;
  int rb = c0 + nn; if (rb > HW-1) rb = HW-1;

  // preload chunk 0 into registers
  uint4 va[4], vb[4], na[4], nb[4];
  {
    const uint4* ga = (const uint4*)(A_h + (size_t)ra*Cc + half*32);
    const uint4* gb = (const uint4*)(B_h + (size_t)rb*Cc + half*32);
    va[0]=ga[0]; va[1]=ga[1]; va[2]=ga[2]; va[3]=ga[3];
    vb[0]=gb[0]; vb[1]=gb[1]; vb[2]=gb[2]; vb[3]=gb[3];
  }
  int base = nn*128 + half*64;
  int sw = (nn & 7) << 4;
  #pragma unroll
  for (int cc = 0; cc < 9; ++cc){
    __syncthreads();                    // previous chunk's frag readers done
    // issue NEXT chunk's loads first: they stay in flight through LDS-write + MFMA
    if (cc < 8){
      int c2 = cc + 1, seg2 = c2/3, k2 = (c2%3)*64;
      const unsigned short* As2 = (seg2 < 2 ? A_h : A_l);
      const unsigned short* Bs2 = (seg2 == 1 ? B_l : B_h);
      const uint4* ga = (const uint4*)(As2 + (size_t)ra*Cc + k2 + half*32);
      const uint4* gb = (const uint4*)(Bs2 + (size_t)rb*Cc + k2 + half*32);
      na[0]=ga[0]; na[1]=ga[1]; na[2]=ga[2]; na[3]=ga[3];
      nb[0]=gb[0]; nb[1]=gb[1]; nb[2]=gb[2]; nb[3]=gb[3];
    }
    // write current chunk (waits only on va/vb's older load group)
    *(uint4*)((char*)Als + ((base      ) ^ sw)) = va[0];
    *(uint4*)((char*)Als + ((base + 16 ) ^ sw)) = va[1];
    *(uint4*)((char*)Als + ((base + 32 ) ^ sw)) = va[2];
    *(uint4*)((char*)Als + ((base + 48 ) ^ sw)) = va[3];
    *(uint4*)((char*)Bls + ((base      ) ^ sw)) = vb[0];
    *(uint4*)((char*)Bls + ((base + 16 ) ^ sw)) = vb[1];
    *(uint4*)((char*)Bls + ((base + 32 ) ^ sw)) = vb[2];
    *(uint4*)((char*)Bls + ((base + 48 ) ^ sw)) = vb[3];
    __syncthreads();
    #pragma unroll
    for (int ks = 0; ks < 2; ++ks){
      bf16x8 af[4], bfr[4];
      int kb = ks*64 + (l >> 4)*16;
      #pragma unroll
      for (int mt = 0; mt < 4; ++mt){
        int rl = wr*64 + mt*16 + (l & 15);
        int off = (rl*128 + kb) ^ ((rl & 7) << 4);
        af[mt] = *(const bf16x8*)((const char*)Als + off);
      }
      #pragma unroll
      for (int nt = 0; nt < 4; ++nt){
        int cl2 = wc*64 + nt*16 + (l & 15);
        int off = (cl2*128 + kb) ^ ((cl2 & 7) << 4);
        bfr[nt] = *(const bf16x8*)((const char*)Bls + off);
      }
      #pragma unroll
      for (int mt = 0; mt < 4; ++mt)
        #pragma unroll
        for (int nt = 0; nt < 4; ++nt)
          acc[mt][nt] = __builtin_amdgcn_mfma_f32_16x16x32_bf16(af[mt], bfr[nt], acc[mt][nt], 0, 0, 0);
    }
    if (cc < 8){
      va[0]=na[0]; va[1]=na[1]; va[2]=na[2]; va[3]=na[3];
      vb[0]=nb[0]; vb[1]=nb[1]; vb[2]=nb[2]; vb[3]=nb[3];
    }
  }
  if (isGram){
    // normal write: D[r0+row][c0+col] = -acc
    #pragma unroll
    for (int mt = 0; mt < 4; ++mt){
      #pragma unroll
      for (int nt = 0; nt < 4; ++nt){
        int col = c0 + wc*64 + nt*16 + (l & 15);
        if (col >= HW) continue;
        int row0 = r0 + wr*64 + mt*16 + ((l >> 4) << 2);
        #pragma unroll
        for (int r = 0; r < 4; ++r){
          int row = row0 + r;
          if (row < HW) D[((size_t)b*HW + row)*HW + col] = -acc[mt][nt][r];
        }
      }
    }
    if (tx > ty){
      // mirror write: D[c0+col][r0+row] = -acc (transposed), LDS-staged per nt quarter.
      #pragma unroll
      for (int nt = 0; nt < 4; ++nt){
        __syncthreads();
        int ci = wc*16 + (l & 15);     // 0..31 within quarter
        #pragma unroll
        for (int mt = 0; mt < 4; ++mt){
          int row = wr*64 + mt*16 + ((l >> 4) << 2);
          #pragma unroll
          for (int r = 0; r < 4; ++r)
            Tt[ci*129 + row + r] = -acc[mt][nt][r];
        }
        __syncthreads();
        int ci2 = t >> 3;              // 0..31
        int col = c0 + (ci2 >> 4)*64 + nt*16 + (ci2 & 15);
        if (col < HW){
          float* Drow = D + ((size_t)b*HW + col)*HW + r0;
          int rbase = (t & 7)*16;
          #pragma unroll
          for (int j = 0; j < 4; ++j){
            int rr = rbase + j*4;
            float4 v = make_float4(Tt[ci2*129 + rr],     Tt[ci2*129 + rr + 1],
                                   Tt[ci2*129 + rr + 2], Tt[ci2*129 + rr + 3]);
            *(float4*)(Drow + rr) = v;
          }
        }
      }
    }
  } else {
    #pragma unroll
    for (int mt = 0; mt < 4; ++mt){
      #pragma unroll
      for (int nt = 0; nt < 4; ++nt){
        int col = c0 + wc*64 + nt*16 + (l & 15);
        if (col >= HW) continue;
        int row0 = r0 + wr*64 + mt*16 + ((l >> 4) << 2);
        #pragma unroll
        for (int r = 0; r < 4; ++r){
          PQ[((size_t)b*768 + row0 + r)*HW + col] = acc[mt][nt][r];
        }
      }
    }
  }
}

// ---- 8. top-9 selection: one wave per row; float4 loads; idx stored [k][b*HW+n] ----
__global__ __launch_bounds__(256) void k_select(const float* __restrict__ D, int* __restrict__ idxo){
  int wid = threadIdx.x >> 6, lane = threadIdx.x & 63;
  int row = blockIdx.x * 4 + wid;            // [0, B*HW)
  const float* Dr = D + (size_t)row * HW;
  const float4* Dr4 = (const float4*)Dr;
  float dvv[13]; int mvv[13];
  #pragma unroll
  for (int j = 0; j < 3; ++j){               // m = 4*(lane+64j)+e, ascending in slot index
    float4 v = Dr4[lane + 64*j];
    int m0 = 4*(lane + 64*j);
    dvv[j*4+0] = v.x; mvv[j*4+0] = m0;
    dvv[j*4+1] = v.y; mvv[j*4+1] = m0+1;
    dvv[j*4+2] = v.z; mvv[j*4+2] = m0+2;
    dvv[j*4+3] = v.w; mvv[j*4+3] = m0+3;
  }
  {
    int m = 768 + lane;                      // leftover 768..783 (lanes 0..15)
    dvv[12] = (m < HW) ? Dr[m] : 3.4e38f;
    mvv[12] = m;
  }
  for (int k = 0; k < KK; ++k){
    float bd = dvv[0]; int bi = 0;
    #pragma unroll
    for (int i = 1; i < 13; ++i) if (dvv[i] < bd){ bd = dvv[i]; bi = i; }
    unsigned long long key = ((unsigned long long)f2ord(bd) << 32) | (unsigned)mvv[bi];
    for (int off = 32; off; off >>= 1){
      unsigned long long o = __shfl_xor(key, off);
      if (o < key) key = o;
    }
    int wm = (int)(unsigned)(key & 0xffffffffu);
    if (lane == 0) idxo[(size_t)k*(Bb*HW) + row] = wm;
    if (mvv[bi] == wm) dvv[bi] = 3.4e38f;
  }
}

// ---- 9. epilogue: Q rows staged in LDS; coalesced idx; amortized over 8 o ----
__global__ __launch_bounds__(256) void k_edge(const float* __restrict__ PQ, const int* __restrict__ idx,
                                              const float* __restrict__ be, float* __restrict__ out){
  int bid = blockIdx.x;
  int b = bid / (CO/OG), og = bid % (CO/OG);
  int o0 = og * OG;
  __shared__ float Qls[OG][HW + 4];
  const float* Qbase = PQ + ((size_t)b*768 + CO + o0)*HW;
  int t = threadIdx.x;
  #pragma unroll
  for (int oo = 0; oo < OG; ++oo){
    if (t < 196) *(float4*)&Qls[oo][t*4] = *(const float4*)(Qbase + (size_t)oo*HW + t*4);
  }
  __syncthreads();
  const float* Pbase = PQ + ((size_t)b*768 + o0)*HW;
  float bev[OG];
  #pragma unroll
  for (int oo = 0; oo < OG; ++oo) bev[oo] = be[o0 + oo];
  for (int n = t; n < HW; n += 256){
    int ip[KK];
    #pragma unroll
    for (int k = 0; k < KK; ++k) ip[k] = idx[(size_t)k*(Bb*HW) + b*HW + n];
    float qm[OG];
    #pragma unroll
    for (int oo = 0; oo < OG; ++oo) qm[oo] = -3.4e38f;
    #pragma unroll
    for (int k = 0; k < KK; ++k){
      int j = ip[k];
      #pragma unroll
      for (int oo = 0; oo < OG; ++oo) qm[oo] = fmaxf(qm[oo], Qls[oo][j]);
    }
    #pragma unroll
    for (int oo = 0; oo < OG; ++oo){
      out[((size_t)b*CO + o0 + oo)*HW + n] = fmaxf(Pbase[(size_t)oo*HW + n] + bev[oo] + qm[oo], 0.f);
    }
  }
}

extern "C" void kernel_launch(void* const* d_in, const int* in_sizes, int n_in,
                              void* d_out, int out_size, void* d_ws, size_t ws_size,
                              hipStream_t stream){
  const float* x   = (const float*)d_in[0];
  const float* we  = (const float*)d_in[1];
  const float* be  = (const float*)d_in[2];
  const float* w1  = (const float*)d_in[3];
  const float* b1  = (const float*)d_in[4];
  const float* w2  = (const float*)d_in[5];
  const float* b2  = (const float*)d_in[6];
  const float* wsp = (const float*)d_in[7];
  const float* bsp = (const float*)d_in[8];
  float* out = (float*)d_out;

  // workspace layout (~99 MiB of 256 MiB ws)
  float* ws    = (float*)d_ws;
  float* chm   = ws;                     // 3072
  float* chx   = chm + 3072;             // 3072
  float* chv   = chx + 3072;             // 3072
  float* vmaxA = chv + 3072;             // 3072
  float* invA  = vmaxA + 3072;           // 3072
  float* amean = invA + 3072;            // 12544
  float* amax  = amean + 12544;          // 12544
  float* satt  = amax + 12544;           // 12544
  float* nrm   = satt + 12544;           // 12544
  unsigned short* Wph = (unsigned short*)(nrm + 12544);    // 147456 ushorts
  unsigned short* Wpl = Wph + 147456;                      // 147456 ushorts
  unsigned short* Xnh = Wpl + 147456;    // 2408448 ushorts
  unsigned short* Xnl = Xnh + 2408448;   // 2408448 ushorts
  unsigned short* XAh = Xnl + 2408448;   // 2408448 ushorts
  unsigned short* XAl = XAh + 2408448;   // 2408448 ushorts
  int*   idx   = (int*)(XAl + 2408448);  // 112896 ints, layout [k][b*HW+n]
  float* D     = (float*)(idx + 112896); // 9834496 floats
  float* PQ    = D + 9834496;            // 9633792 floats (independent)

  k_chstats<<<768, 256, 0, stream>>>(x, chm, chx);
  k_mlp<<<16, 192, 0, stream>>>(chm, chx, w1, b1, w2, b2, chv);
  k_spin<<<64, 256, 0, stream>>>(x, chv, amean, amax, nrm);
  k_conv<<<64, 256, 0, stream>>>(amean, amax, wsp, bsp, satt);
  k_attstats<<<768, 256, 0, stream>>>(x, chv, satt, vmaxA, invA);
  k_cvt2wp<<<1200, 256, 0, stream>>>(x, nrm, chv, satt, vmaxA, invA, we,
                                     Xnh, Xnl, XAh, XAl, Wph, Wpl);
  k_gramgemm<<<1120, 256, 0, stream>>>(Xnh, Xnl, Wph, Wpl, XAh, XAl, D, PQ);
  k_select<<<3136, 256, 0, stream>>>(D, idx);
  k_edge<<<Bb*(CO/OG), 256, 0, stream>>>(PQ, idx, be, out);
}

// Round 14
// 138.186 us; speedup vs baseline: 2.0282x; 2.0282x over previous
//
#include <hip/hip_runtime.h>
#include <math.h>

#define HW 784
#define Cc 192
#define Bb 16
#define CO 384
#define KK 9
#define OG 8

typedef __attribute__((ext_vector_type(8))) short bf16x8;
typedef __attribute__((ext_vector_type(4))) float f32x4;

__device__ __forceinline__ unsigned f2ord(float f){
  unsigned u = __float_as_uint(f);
  return (u & 0x80000000u) ? ~u : (u | 0x80000000u);
}

__device__ __forceinline__ unsigned short b16rne(float v){
  unsigned u = __float_as_uint(v);
  unsigned r = u + 0x7FFFu + ((u >> 16) & 1u);
  return (unsigned short)(r >> 16);
}

// ---- 1. per-(b,c) mean & max over HW (float4 rows) ----
__global__ void k_chstats(const float* __restrict__ x, float* __restrict__ chm, float* __restrict__ chx){
  int wid = threadIdx.x >> 6, lane = threadIdx.x & 63;
  int r = blockIdx.x * 4 + wid;               // r in [0, B*C)
  const float4* row = (const float4*)(x + (size_t)r * HW);   // 196 float4s
  float s = 0.f, m = -3.4e38f;
  #pragma unroll
  for (int i = 0; i < 4; ++i){
    int f4 = lane + 64*i;
    if (f4 < 196){
      float4 v = row[f4];
      s += v.x + v.y + v.z + v.w;
      m = fmaxf(m, fmaxf(fmaxf(v.x, v.y), fmaxf(v.z, v.w)));
    }
  }
  for (int off = 32; off; off >>= 1){ s += __shfl_xor(s, off); m = fmaxf(m, __shfl_xor(m, off)); }
  if (lane == 0){ chm[r] = s / (float)HW; chx[r] = m; }
}

// ---- 2. channel-attention MLP: ch = sigmoid(mlp(mean)+mlp(max)) ----
__global__ void k_mlp(const float* __restrict__ chm, const float* __restrict__ chx,
                      const float* __restrict__ w1, const float* __restrict__ b1,
                      const float* __restrict__ w2, const float* __restrict__ b2,
                      float* __restrict__ chv){
  int b = blockIdx.x, t = threadIdx.x;
  __shared__ float vm[Cc], vx[Cc], hp[2][12];
  if (t < Cc){ vm[t] = chm[b*Cc + t]; vx[t] = chx[b*Cc + t]; }
  __syncthreads();
  if (t < 24){
    int h = t % 12;
    const float* src = (t < 12) ? vm : vx;
    float a = b1[h];
    for (int c = 0; c < Cc; ++c) a += src[c] * w1[h*Cc + c];
    hp[t/12][h] = fmaxf(a, 0.f);
  }
  __syncthreads();
  if (t < Cc){
    float a = 2.f * b2[t];
    for (int h = 0; h < 12; ++h) a += (hp[0][h] + hp[1][h]) * w2[t*12 + h];
    chv[b*Cc + t] = 1.f / (1.f + expf(-a));
  }
}

// ---- 3. spatial mean/max over C of x*ch  +  column norms of x (fused) ----
__global__ void k_spin(const float* __restrict__ x, const float* __restrict__ chv,
                       float* __restrict__ amean, float* __restrict__ amax,
                       float* __restrict__ nrm){
  int b = blockIdx.x >> 2;
  int n = ((blockIdx.x & 3) << 8) + threadIdx.x;
  if (n >= HW) return;
  const float* xb = x + (size_t)b*Cc*HW + n;
  const float* cb = chv + b*Cc;
  float s = 0.f, m = -3.4e38f, sq = 0.f;
  for (int c = 0; c < Cc; ++c){
    float xv = xb[(size_t)c*HW];
    float v = xv * cb[c];
    s += v; m = fmaxf(m, v); sq += xv*xv;
  }
  amean[b*HW + n] = s / (float)Cc;
  amax[b*HW + n]  = m;
  nrm[b*HW + n]   = fmaxf(sqrtf(sq), 1e-12f);
}

// ---- 4. 7x7 conv (2 in-ch) + sigmoid ----
__global__ void k_conv(const float* __restrict__ amean, const float* __restrict__ amax,
                       const float* __restrict__ wsp, const float* __restrict__ bsp,
                       float* __restrict__ satt){
  int b = blockIdx.x >> 2;
  int n = ((blockIdx.x & 3) << 8) + threadIdx.x;
  if (n >= HW) return;
  int yy = n / 28, xx = n % 28;
  float a = 0.f;
  for (int ky = 0; ky < 7; ++ky){
    int iy = yy + ky - 3; if (iy < 0 || iy >= 28) continue;
    for (int kx = 0; kx < 7; ++kx){
      int ix = xx + kx - 3; if (ix < 0 || ix >= 28) continue;
      int ii = b*HW + iy*28 + ix;
      a += amean[ii]*wsp[ky*7 + kx] + amax[ii]*wsp[49 + ky*7 + kx];
    }
  }
  satt[b*HW + n] = 1.f / (1.f + expf(-(a + bsp[0])));
}

// ---- 5. attention softmax stats per (b,c): vmax and inv = 1/(1+EPS*S)  (float4 rows) ----
__global__ void k_attstats(const float* __restrict__ x, const float* __restrict__ chv,
                           const float* __restrict__ satt,
                           float* __restrict__ vmaxA, float* __restrict__ invA){
  int wid = threadIdx.x >> 6, lane = threadIdx.x & 63;
  int r = blockIdx.x * 4 + wid;               // b*Cc + c
  int b = r / Cc;
  const float4* row = (const float4*)(x + (size_t)r * HW);
  const float4* sr  = (const float4*)(satt + b * HW);
  float ch = chv[r];
  float4 vv[4];
  float m = -3.4e38f;
  #pragma unroll
  for (int i = 0; i < 4; ++i){
    int f4 = lane + 64*i;
    if (f4 < 196){
      float4 xv = row[f4], sv = sr[f4];
      vv[i].x = (xv.x * ch) * sv.x; vv[i].y = (xv.y * ch) * sv.y;
      vv[i].z = (xv.z * ch) * sv.z; vv[i].w = (xv.w * ch) * sv.w;
      m = fmaxf(m, fmaxf(fmaxf(vv[i].x, vv[i].y), fmaxf(vv[i].z, vv[i].w)));
    }
  }
  for (int off = 32; off; off >>= 1) m = fmaxf(m, __shfl_xor(m, off));
  float s = 0.f;
  #pragma unroll
  for (int i = 0; i < 4; ++i){
    int f4 = lane + 64*i;
    if (f4 < 196){
      s += expf(vv[i].x - m) + expf(vv[i].y - m) + expf(vv[i].z - m) + expf(vv[i].w - m);
    }
  }
  for (int off = 32; off; off >>= 1) s += __shfl_xor(s, off);
  if (lane == 0){ vmaxA[r] = m; invA[r] = 1.f / (1.f + 1e-10f * s); }
}

// ---- 6. merged: transpose+split pass (blocks 0..623)  |  weight prep (blocks 624..1199) ----
__global__ __launch_bounds__(256) void k_cvt2wp(const float* __restrict__ x, const float* __restrict__ nrm,
                                                const float* __restrict__ chv, const float* __restrict__ satt,
                                                const float* __restrict__ vmaxA, const float* __restrict__ invA,
                                                const float* __restrict__ we,
                                                unsigned short* __restrict__ Xnh, unsigned short* __restrict__ Xnl,
                                                unsigned short* __restrict__ XAh, unsigned short* __restrict__ XAl,
                                                unsigned short* __restrict__ Wph, unsigned short* __restrict__ Wpl){
  int bid = blockIdx.x, t = threadIdx.x;
  if (bid >= 624){                         // ---- weight prep path ----
    int i = (bid - 624)*256 + t;           // < 147456 exactly
    int o = i / Cc, c = i % Cc;
    float v = (o < CO) ? (we[(size_t)o*384 + c] - we[(size_t)o*384 + Cc + c])
                       : we[(size_t)(o - CO)*384 + Cc + c];
    unsigned short h = b16rne(v);
    float lo = v - __uint_as_float((unsigned)h << 16);
    Wph[i] = h;
    Wpl[i] = b16rne(lo);
    return;
  }
  // ---- transpose + split path ----
  int xx = bid % 13, yy = (bid / 13) % 3, b = bid / 39;
  int c0 = yy*64, n0 = xx*64;
  __shared__ float T[64][65];
  __shared__ float chs[64], vms[64], ivs[64];
  int nl = (t & 15) * 4, cl = t >> 4;
  const float* xb = x + (size_t)b*Cc*HW;
  #pragma unroll
  for (int r = 0; r < 4; ++r){
    int c_loc = cl + r*16;
    int n = n0 + nl;
    float4 v = (n < HW) ? *(const float4*)(xb + (size_t)(c0 + c_loc)*HW + n) : make_float4(0,0,0,0);
    *(float4*)&T[c_loc][nl] = v;
  }
  if (t < 64){
    chs[t] = chv[b*Cc + c0 + t];
    vms[t] = vmaxA[b*Cc + c0 + t];
    ivs[t] = invA[b*Cc + c0 + t];
  }
  __syncthreads();
  int nr = t >> 2, q = t & 3;
  int n_g = n0 + nr;
  if (n_g >= HW) return;
  float nv = nrm[b*HW + n_g];
  float sr = satt[b*HW + n_g];
  unsigned int nh[8], nlw[8], ah[8], al[8];
  #pragma unroll
  for (int j = 0; j < 8; ++j){
    unsigned int parts[2][2];
    #pragma unroll
    for (int e = 0; e < 2; ++e){
      int cc_ = q*16 + 2*j + e;
      float v = T[cc_][nr];
      float xnv = v / nv;
      unsigned short h0 = b16rne(xnv);
      float l0 = xnv - __uint_as_float((unsigned)h0 << 16);
      parts[0][e] = (unsigned)h0 | ((unsigned)b16rne(l0) << 16);
      float vvv = (v * chs[cc_]) * sr;
      float ex = expf(vvv - vms[cc_]);
      float a = ex * ivs[cc_];
      float xav = v * ((2.f*a - 1.f)*0.025f + 1.f);
      unsigned short h1 = b16rne(xav);
      float l1 = xav - __uint_as_float((unsigned)h1 << 16);
      parts[1][e] = (unsigned)h1 | ((unsigned)b16rne(l1) << 16);
    }
    nh[j]  = (parts[0][0] & 0xFFFFu) | (parts[0][1] << 16);
    nlw[j] = (parts[0][0] >> 16)     | (parts[0][1] & 0xFFFF0000u);
    ah[j]  = (parts[1][0] & 0xFFFFu) | (parts[1][1] << 16);
    al[j]  = (parts[1][0] >> 16)     | (parts[1][1] & 0xFFFF0000u);
  }
  size_t base = ((size_t)b*HW + n_g)*Cc + c0 + q*16;
  *(uint4*)(Xnh + base)     = make_uint4(nh[0], nh[1], nh[2], nh[3]);
  *(uint4*)(Xnh + base + 8) = make_uint4(nh[4], nh[5], nh[6], nh[7]);
  *(uint4*)(Xnl + base)     = make_uint4(nlw[0], nlw[1], nlw[2], nlw[3]);
  *(uint4*)(Xnl + base + 8) = make_uint4(nlw[4], nlw[5], nlw[6], nlw[7]);
  *(uint4*)(XAh + base)     = make_uint4(ah[0], ah[1], ah[2], ah[3]);
  *(uint4*)(XAh + base + 8) = make_uint4(ah[4], ah[5], ah[6], ah[7]);
  *(uint4*)(XAl + base)     = make_uint4(al[0], al[1], al[2], al[3]);
  *(uint4*)(XAl + base + 8) = make_uint4(al[4], al[5], al[6], al[7]);
}

// ---- 7. merged MFMA launch, XCD-swizzled, symmetric gram, T14 rotation pipeline:
//      per chunk {barrier; ds_write staged regs (vmcnt wait hidden behind prev MFMA);
//      issue next loads; barrier; MFMA}. Named scalars only; launch_bounds(256,1)
//      lifts the VGPR cap so nothing spills. ----
__global__ __launch_bounds__(256, 1) void k_gramgemm(const unsigned short* __restrict__ Xnh,
                                                     const unsigned short* __restrict__ Xnl,
                                                     const unsigned short* __restrict__ Wph,
                                                     const unsigned short* __restrict__ Wpl,
                                                     const unsigned short* __restrict__ XAh,
                                                     const unsigned short* __restrict__ XAl,
                                                     float* __restrict__ D, float* __restrict__ PQ){
  __shared__ __align__(16) char smem[32768];
  unsigned short* Als = (unsigned short*)smem;          // 8192 ushorts
  unsigned short* Bls = Als + 8192;                     // 8192 ushorts
  float* Tt = (float*)smem;                             // mirror-transpose staging (16.5KB)

  int hwbid = blockIdx.x;
  int bid = (hwbid & 7) * 140 + (hwbid >> 3);           // XCD-chunk swizzle (bijective, 1120=8*140)
  int t = threadIdx.x, w = t >> 6, l = t & 63;
  int wr = w >> 1, wc = w & 1;
  f32x4 acc[4][4] = {};
  int nn = t >> 1, half = t & 1;

  bool isGram = bid < 448;
  int b, r0, c0, ty = 0, tx = 0;
  const unsigned short *A_h, *A_l, *B_h, *B_l;
  if (isGram){
    b = bid / 28; int rm = bid % 28;
    if      (rm <  7){ ty=0; tx=rm; }
    else if (rm < 13){ ty=1; tx=1+rm-7; }
    else if (rm < 18){ ty=2; tx=2+rm-13; }
    else if (rm < 22){ ty=3; tx=3+rm-18; }
    else if (rm < 25){ ty=4; tx=4+rm-22; }
    else if (rm < 27){ ty=5; tx=5+rm-25; }
    else             { ty=6; tx=6; }
    r0 = ty*128; c0 = tx*128;
    size_t bb = (size_t)b*HW*Cc;
    A_h = Xnh + bb; A_l = Xnl + bb; B_h = Xnh + bb; B_l = Xnl + bb;
  } else {
    int id = bid - 448;
    b = id / 42; int rem = id % 42;
    c0 = (rem % 7) * 128; r0 = (rem / 7) * 128;
    size_t bb = (size_t)b*HW*Cc;
    A_h = Wph; A_l = Wpl; B_h = XAh + bb; B_l = XAl + bb;
  }
  int ra = r0 + nn; if (isGram && ra > HW-1) ra = HW-1;
  int rb = c0 + nn; if (rb > HW-1) rb = HW-1;

  // prologue: load chunk 0 into named scalar registers
  uint4 va0, va1, va2, va3, vb0, vb1, vb2, vb3;
  {
    const uint4* ga = (const uint4*)(A_h + (size_t)ra*Cc + half*32);
    const uint4* gb = (const uint4*)(B_h + (size_t)rb*Cc + half*32);
    va0=ga[0]; va1=ga[1]; va2=ga[2]; va3=ga[3];
    vb0=gb[0]; vb1=gb[1]; vb2=gb[2]; vb3=gb[3];
  }
  int base = nn*128 + half*64;
  int sw = (nn & 7) << 4;
  for (int cc = 0; cc < 9; ++cc){
    __syncthreads();                    // previous chunk's frag readers done; LDS free
    // write staged regs (compiler inserts the vmcnt wait HERE — it was issued one
    // MFMA-phase ago, so the latency is already paid)
    *(uint4*)((char*)Als + ((base      ) ^ sw)) = va0;
    *(uint4*)((char*)Als + ((base + 16 ) ^ sw)) = va1;
    *(uint4*)((char*)Als + ((base + 32 ) ^ sw)) = va2;
    *(uint4*)((char*)Als + ((base + 48 ) ^ sw)) = va3;
    *(uint4*)((char*)Bls + ((base      ) ^ sw)) = vb0;
    *(uint4*)((char*)Bls + ((base + 16 ) ^ sw)) = vb1;
    *(uint4*)((char*)Bls + ((base + 32 ) ^ sw)) = vb2;
    *(uint4*)((char*)Bls + ((base + 48 ) ^ sw)) = vb3;
    // issue NEXT chunk's loads into the same registers; they fly through the
    // barrier + MFMA below and are waited at the next iteration's ds_write
    if (cc < 8){
      int c2 = cc + 1, seg2 = c2/3, k2 = (c2%3)*64;
      const unsigned short* As2 = (seg2 < 2 ? A_h : A_l);
      const unsigned short* Bs2 = (seg2 == 1 ? B_l : B_h);
      const uint4* ga = (const uint4*)(As2 + (size_t)ra*Cc + k2 + half*32);
      const uint4* gb = (const uint4*)(Bs2 + (size_t)rb*Cc + k2 + half*32);
      va0=ga[0]; va1=ga[1]; va2=ga[2]; va3=ga[3];
      vb0=gb[0]; vb1=gb[1]; vb2=gb[2]; vb3=gb[3];
    }
    __syncthreads();
    #pragma unroll
    for (int ks = 0; ks < 2; ++ks){
      bf16x8 af[4], bfr[4];
      int kb = ks*64 + (l >> 4)*16;
      #pragma unroll
      for (int mt = 0; mt < 4; ++mt){
        int rl = wr*64 + mt*16 + (l & 15);
        int off = (rl*128 + kb) ^ ((rl & 7) << 4);
        af[mt] = *(const bf16x8*)((const char*)Als + off);
      }
      #pragma unroll
      for (int nt = 0; nt < 4; ++nt){
        int cl2 = wc*64 + nt*16 + (l & 15);
        int off = (cl2*128 + kb) ^ ((cl2 & 7) << 4);
        bfr[nt] = *(const bf16x8*)((const char*)Bls + off);
      }
      #pragma unroll
      for (int mt = 0; mt < 4; ++mt)
        #pragma unroll
        for (int nt = 0; nt < 4; ++nt)
          acc[mt][nt] = __builtin_amdgcn_mfma_f32_16x16x32_bf16(af[mt], bfr[nt], acc[mt][nt], 0, 0, 0);
    }
  }
  if (isGram){
    // normal write: D[r0+row][c0+col] = -acc
    #pragma unroll
    for (int mt = 0; mt < 4; ++mt){
      #pragma unroll
      for (int nt = 0; nt < 4; ++nt){
        int col = c0 + wc*64 + nt*16 + (l & 15);
        if (col >= HW) continue;
        int row0 = r0 + wr*64 + mt*16 + ((l >> 4) << 2);
        #pragma unroll
        for (int r = 0; r < 4; ++r){
          int row = row0 + r;
          if (row < HW) D[((size_t)b*HW + row)*HW + col] = -acc[mt][nt][r];
        }
      }
    }
    if (tx > ty){
      // mirror write: D[c0+col][r0+row] = -acc (transposed), LDS-staged per nt quarter.
      #pragma unroll
      for (int nt = 0; nt < 4; ++nt){
        __syncthreads();
        int ci = wc*16 + (l & 15);     // 0..31 within quarter
        #pragma unroll
        for (int mt = 0; mt < 4; ++mt){
          int row = wr*64 + mt*16 + ((l >> 4) << 2);
          #pragma unroll
          for (int r = 0; r < 4; ++r)
            Tt[ci*129 + row + r] = -acc[mt][nt][r];
        }
        __syncthreads();
        int ci2 = t >> 3;              // 0..31
        int col = c0 + (ci2 >> 4)*64 + nt*16 + (ci2 & 15);
        if (col < HW){
          float* Drow = D + ((size_t)b*HW + col)*HW + r0;
          int rbase = (t & 7)*16;
          #pragma unroll
          for (int j = 0; j < 4; ++j){
            int rr = rbase + j*4;
            float4 v = make_float4(Tt[ci2*129 + rr],     Tt[ci2*129 + rr + 1],
                                   Tt[ci2*129 + rr + 2], Tt[ci2*129 + rr + 3]);
            *(float4*)(Drow + rr) = v;
          }
        }
      }
    }
  } else {
    #pragma unroll
    for (int mt = 0; mt < 4; ++mt){
      #pragma unroll
      for (int nt = 0; nt < 4; ++nt){
        int col = c0 + wc*64 + nt*16 + (l & 15);
        if (col >= HW) continue;
        int row0 = r0 + wr*64 + mt*16 + ((l >> 4) << 2);
        #pragma unroll
        for (int r = 0; r < 4; ++r){
          PQ[((size_t)b*768 + row0 + r)*HW + col] = acc[mt][nt][r];
        }
      }
    }
  }
}

// ---- 8. top-9 selection: one wave per row; float4 loads; idx stored [k][b*HW+n] ----
__global__ __launch_bounds__(256) void k_select(const float* __restrict__ D, int* __restrict__ idxo){
  int wid = threadIdx.x >> 6, lane = threadIdx.x & 63;
  int row = blockIdx.x * 4 + wid;            // [0, B*HW)
  const float* Dr = D + (size_t)row * HW;
  const float4* Dr4 = (const float4*)Dr;
  float dvv[13]; int mvv[13];
  #pragma unroll
  for (int j = 0; j < 3; ++j){               // m = 4*(lane+64j)+e, ascending in slot index
    float4 v = Dr4[lane + 64*j];
    int m0 = 4*(lane + 64*j);
    dvv[j*4+0] = v.x; mvv[j*4+0] = m0;
    dvv[j*4+1] = v.y; mvv[j*4+1] = m0+1;
    dvv[j*4+2] = v.z; mvv[j*4+2] = m0+2;
    dvv[j*4+3] = v.w; mvv[j*4+3] = m0+3;
  }
  {
    int m = 768 + lane;                      // leftover 768..783 (lanes 0..15)
    dvv[12] = (m < HW) ? Dr[m] : 3.4e38f;
    mvv[12] = m;
  }
  for (int k = 0; k < KK; ++k){
    float bd = dvv[0]; int bi = 0;
    #pragma unroll
    for (int i = 1; i < 13; ++i) if (dvv[i] < bd){ bd = dvv[i]; bi = i; }
    unsigned long long key = ((unsigned long long)f2ord(bd) << 32) | (unsigned)mvv[bi];
    for (int off = 32; off; off >>= 1){
      unsigned long long o = __shfl_xor(key, off);
      if (o < key) key = o;
    }
    int wm = (int)(unsigned)(key & 0xffffffffu);
    if (lane == 0) idxo[(size_t)k*(Bb*HW) + row] = wm;
    if (mvv[bi] == wm) dvv[bi] = 3.4e38f;
  }
}

// ---- 9. epilogue: Q rows staged in LDS; coalesced idx; amortized over 8 o ----
__global__ __launch_bounds__(256) void k_edge(const float* __restrict__ PQ, const int* __restrict__ idx,
                                              const float* __restrict__ be, float* __restrict__ out){
  int bid = blockIdx.x;
  int b = bid / (CO/OG), og = bid % (CO/OG);
  int o0 = og * OG;
  __shared__ float Qls[OG][HW + 4];
  const float* Qbase = PQ + ((size_t)b*768 + CO + o0)*HW;
  int t = threadIdx.x;
  #pragma unroll
  for (int oo = 0; oo < OG; ++oo){
    if (t < 196) *(float4*)&Qls[oo][t*4] = *(const float4*)(Qbase + (size_t)oo*HW + t*4);
  }
  __syncthreads();
  const float* Pbase = PQ + ((size_t)b*768 + o0)*HW;
  float bev[OG];
  #pragma unroll
  for (int oo = 0; oo < OG; ++oo) bev[oo] = be[o0 + oo];
  for (int n = t; n < HW; n += 256){
    int ip[KK];
    #pragma unroll
    for (int k = 0; k < KK; ++k) ip[k] = idx[(size_t)k*(Bb*HW) + b*HW + n];
    float qm[OG];
    #pragma unroll
    for (int oo = 0; oo < OG; ++oo) qm[oo] = -3.4e38f;
    #pragma unroll
    for (int k = 0; k < KK; ++k){
      int j = ip[k];
      #pragma unroll
      for (int oo = 0; oo < OG; ++oo) qm[oo] = fmaxf(qm[oo], Qls[oo][j]);
    }
    #pragma unroll
    for (int oo = 0; oo < OG; ++oo){
      out[((size_t)b*CO + o0 + oo)*HW + n] = fmaxf(Pbase[(size_t)oo*HW + n] + bev[oo] + qm[oo], 0.f);
    }
  }
}

extern "C" void kernel_launch(void* const* d_in, const int* in_sizes, int n_in,
                              void* d_out, int out_size, void* d_ws, size_t ws_size,
                              hipStream_t stream){
  const float* x   = (const float*)d_in[0];
  const float* we  = (const float*)d_in[1];
  const float* be  = (const float*)d_in[2];
  const float* w1  = (const float*)d_in[3];
  const float* b1  = (const float*)d_in[4];
  const float* w2  = (const float*)d_in[5];
  const float* b2  = (const float*)d_in[6];
  const float* wsp = (const float*)d_in[7];
  const float* bsp = (const float*)d_in[8];
  float* out = (float*)d_out;

  // workspace layout (~99 MiB of 256 MiB ws)
  float* ws    = (float*)d_ws;
  float* chm   = ws;                     // 3072
  float* chx   = chm + 3072;             // 3072
  float* chv   = chx + 3072;             // 3072
  float* vmaxA = chv + 3072;             // 3072
  float* invA  = vmaxA + 3072;           // 3072
  float* amean = invA + 3072;            // 12544
  float* amax  = amean + 12544;          // 12544
  float* satt  = amax + 12544;           // 12544
  float* nrm   = satt + 12544;           // 12544
  unsigned short* Wph = (unsigned short*)(nrm + 12544);    // 147456 ushorts
  unsigned short* Wpl = Wph + 147456;                      // 147456 ushorts
  unsigned short* Xnh = Wpl + 147456;    // 2408448 ushorts
  unsigned short* Xnl = Xnh + 2408448;   // 2408448 ushorts
  unsigned short* XAh = Xnl + 2408448;   // 2408448 ushorts
  unsigned short* XAl = XAh + 2408448;   // 2408448 ushorts
  int*   idx   = (int*)(XAl + 2408448);  // 112896 ints, layout [k][b*HW+n]
  float* D     = (float*)(idx + 112896); // 9834496 floats
  float* PQ    = D + 9834496;            // 9633792 floats (independent)

  k_chstats<<<768, 256, 0, stream>>>(x, chm, chx);
  k_mlp<<<16, 192, 0, stream>>>(chm, chx, w1, b1, w2, b2, chv);
  k_spin<<<64, 256, 0, stream>>>(x, chv, amean, amax, nrm);
  k_conv<<<64, 256, 0, stream>>>(amean, amax, wsp, bsp, satt);
  k_attstats<<<768, 256, 0, stream>>>(x, chv, satt, vmaxA, invA);
  k_cvt2wp<<<1200, 256, 0, stream>>>(x, nrm, chv, satt, vmaxA, invA, we,
                                     Xnh, Xnl, XAh, XAl, Wph, Wpl);
  k_gramgemm<<<1120, 256, 0, stream>>>(Xnh, Xnl, Wph, Wpl, XAh, XAl, D, PQ);
  k_select<<<3136, 256, 0, stream>>>(D, idx);
  k_edge<<<Bb*(CO/OG), 256, 0, stream>>>(PQ, idx, be, out);
}